// Round 1
// baseline (294.002 us; speedup 1.0000x reference)
//
#include <hip/hip_runtime.h>

// WeightingRouter: per row h = x[:,0]
//   h >= 0.3 : [(h-0.3)/0.7, 0, (1-h)/0.7]
//   h <  0.3 : [0, (0.3-h)/0.3, h/0.3]
// Memory-bound map: 8B in, 12B out per row. Process 4 rows/thread:
// 2x float4 loads, 3x float4 stores — fully 16B vectorized & coalesced.

#define THR 0.3f
#define INV_SECOND (1.0f / 0.7f)
#define INV_THR    (1.0f / 0.3f)

__global__ __launch_bounds__(256) void router_quad_kernel(
    const float4* __restrict__ in4, float4* __restrict__ out4, int nquad) {
    int i = blockIdx.x * blockDim.x + threadIdx.x;
    if (i >= nquad) return;

    float4 a = in4[2 * i];       // rows 4i, 4i+1  (h at .x and .z)
    float4 b = in4[2 * i + 1];   // rows 4i+2, 4i+3

    float h[4] = {a.x, a.z, b.x, b.z};
    float o[12];
#pragma unroll
    for (int k = 0; k < 4; ++k) {
        float hv = h[k];
        bool hi = hv >= THR;
        o[3 * k + 0] = hi ? (hv - THR) * INV_SECOND : 0.0f;
        o[3 * k + 1] = hi ? 0.0f : (THR - hv) * INV_THR;
        o[3 * k + 2] = hi ? (1.0f - hv) * INV_SECOND : hv * INV_THR;
    }

    out4[3 * i + 0] = make_float4(o[0], o[1], o[2],  o[3]);
    out4[3 * i + 1] = make_float4(o[4], o[5], o[6],  o[7]);
    out4[3 * i + 2] = make_float4(o[8], o[9], o[10], o[11]);
}

// Scalar tail for rows not covered by the quad kernel (n % 4 != 0).
__global__ void router_tail_kernel(
    const float* __restrict__ in, float* __restrict__ out, int start, int n) {
    int r = start + blockIdx.x * blockDim.x + threadIdx.x;
    if (r >= n) return;
    float hv = in[2 * r];
    bool hi = hv >= THR;
    out[3 * r + 0] = hi ? (hv - THR) * INV_SECOND : 0.0f;
    out[3 * r + 1] = hi ? 0.0f : (THR - hv) * INV_THR;
    out[3 * r + 2] = hi ? (1.0f - hv) * INV_SECOND : hv * INV_THR;
}

extern "C" void kernel_launch(void* const* d_in, const int* in_sizes, int n_in,
                              void* d_out, int out_size, void* d_ws, size_t ws_size,
                              hipStream_t stream) {
    const float* x = (const float*)d_in[0];
    float* out = (float*)d_out;
    int n = in_sizes[0] / 2;          // number of rows
    int nquad = n / 4;                // 4 rows per thread

    if (nquad > 0) {
        int threads = 256;
        int blocks = (nquad + threads - 1) / threads;
        router_quad_kernel<<<blocks, threads, 0, stream>>>(
            (const float4*)x, (float4*)out, nquad);
    }
    int rem = n - nquad * 4;
    if (rem > 0) {
        router_tail_kernel<<<(rem + 255) / 256, 256, 0, stream>>>(
            x, out, nquad * 4, n);
    }
}

// Round 2
// 290.873 us; speedup vs baseline: 1.0108x; 1.0108x over previous
//
#include <hip/hip_runtime.h>

// WeightingRouter: per row h = x[:,0]
//   h >= 0.3 : [(h-0.3)/0.7, 0, (1-h)/0.7]
//   h <  0.3 : [0, (0.3-h)/0.3, h/0.3]
//
// Memory-bound map (8B in, 12B out per row). R2: LDS-staged layout transform
// so BOTH global loads and global stores are lane-contiguous float4:
//   block = 256 threads, 1024 rows/block
//   loads:  in4[base+t], in4[base+256+t]          (perfect 16B coalescing)
//   LDS:    each thread scatters 2x6 floats (stride 6 -> max 2-way bank
//           conflict, which is free on gfx950 per m136)
//   stores: out4[base+t], +256, +512 from LDS     (perfect 16B coalescing)

#define THR 0.3f
#define INV_SECOND (1.0f / 0.7f)
#define INV_THR    (1.0f / 0.3f)

__device__ __forceinline__ void route2(float4 v, float* p) {
    // v holds rows (h0, w0, h1, w1); write 6 output floats to p[0..5]
    float h0 = v.x, h1 = v.z;
    bool c0 = h0 >= THR, c1 = h1 >= THR;
    p[0] = c0 ? (h0 - THR) * INV_SECOND : 0.0f;
    p[1] = c0 ? 0.0f : (THR - h0) * INV_THR;
    p[2] = c0 ? (1.0f - h0) * INV_SECOND : h0 * INV_THR;
    p[3] = c1 ? (h1 - THR) * INV_SECOND : 0.0f;
    p[4] = c1 ? 0.0f : (THR - h1) * INV_THR;
    p[5] = c1 ? (1.0f - h1) * INV_SECOND : h1 * INV_THR;
}

__global__ __launch_bounds__(256) void router_lds_kernel(
    const float4* __restrict__ in4, float4* __restrict__ out4) {
    __shared__ float4 lds4[768];           // 3072 floats = 12 KiB
    float* lds = (float*)lds4;
    int t = threadIdx.x;

    long bi = (long)blockIdx.x * 512;      // input float4 base (1024 rows)
    float4 a = in4[bi + t];                // local rows 2t, 2t+1
    float4 b = in4[bi + 256 + t];          // local rows 512+2t, 512+2t+1

    route2(a, &lds[6 * t]);
    route2(b, &lds[1536 + 6 * t]);
    __syncthreads();

    long bo = (long)blockIdx.x * 768;      // output float4 base
    out4[bo + t]       = lds4[t];
    out4[bo + 256 + t] = lds4[t + 256];
    out4[bo + 512 + t] = lds4[t + 512];
}

// Scalar tail for rows not covered by the LDS kernel (n % 1024 != 0).
__global__ void router_tail_kernel(
    const float* __restrict__ in, float* __restrict__ out, int start, int n) {
    int r = start + blockIdx.x * blockDim.x + threadIdx.x;
    if (r >= n) return;
    float hv = in[2 * r];
    bool hi = hv >= THR;
    out[3 * r + 0] = hi ? (hv - THR) * INV_SECOND : 0.0f;
    out[3 * r + 1] = hi ? 0.0f : (THR - hv) * INV_THR;
    out[3 * r + 2] = hi ? (1.0f - hv) * INV_SECOND : hv * INV_THR;
}

extern "C" void kernel_launch(void* const* d_in, const int* in_sizes, int n_in,
                              void* d_out, int out_size, void* d_ws, size_t ws_size,
                              hipStream_t stream) {
    const float* x = (const float*)d_in[0];
    float* out = (float*)d_out;
    int n = in_sizes[0] / 2;               // number of rows
    int nblk = n / 1024;                   // 1024 rows per block

    if (nblk > 0) {
        router_lds_kernel<<<nblk, 256, 0, stream>>>(
            (const float4*)x, (float4*)out);
    }
    int done = nblk * 1024;
    int rem = n - done;
    if (rem > 0) {
        router_tail_kernel<<<(rem + 255) / 256, 256, 0, stream>>>(
            x, out, done, n);
    }
}